// Round 4
// baseline (623.274 us; speedup 1.0000x reference)
//
#include <hip/hip_runtime.h>
#include <hip/hip_bf16.h>

typedef __bf16 bf16;
typedef __bf16 bf16x8 __attribute__((ext_vector_type(8)));
typedef __bf16 bf16x4 __attribute__((ext_vector_type(4)));
typedef float f32x4 __attribute__((ext_vector_type(4)));

// problem sizes
#define NN 8192
#define DIN 128
#define DTH 256
#define DH 64

// workspace layout (bytes)
#define OFF_PACCS 0                          // [4 js][8192][64] f32 partial agg
#define OFF_PDENS (4*8192*64*4)              // [4 js][8192] f32 partial denom
#define OFF_BN    (OFF_PDENS + 4*8192*4)     // 256 f32 bn sums (needs zero)
#define OFF_HXS   (OFF_BN + 1024)            // swizzled Hx: 8192*256 bf16
#define OFF_X2SW  (OFF_HXS + 8192*256*2)     // swizzled X2: 64*8192 bf16
#define OFF_WCT   (OFF_X2SW + 64*8192*2)     // [384][128] bf16 W concat^T

// Hxs swizzle: element (row, kk) -> ((row>>4)*8 + (kk>>5))*512
//                                   + ((row&15)*4 + ((kk>>3)&3))*8 + (kk&7)
// so MFMA frag (panel p, k): lane(q,li) loads b128 at ((p*8+k)*64 + li*4+q)*8.
// X2sw swizzle: element (c, j) -> ((((j>>6)*4 + (c>>4))*2 + ((j>>5)&1))*16
//                                  + (c&15))*32 + ((j>>3)&3)*8 + (j&7)

#define LGKM_BARRIER() asm volatile("s_waitcnt lgkmcnt(0)\n\ts_barrier" ::: "memory")

// ---------------------------------------------------------------------------
// BN statistics (atomic per-feature sum/sumsq) + cast W -> WcatT bf16.
__global__ __launch_bounds__(256) void k_bn_stats(
    const float* __restrict__ H, float* __restrict__ bns,
    const float* __restrict__ Wt, const float* __restrict__ W1,
    const float* __restrict__ W2, bf16* __restrict__ WcatT)
{
    __shared__ float s1[256], s2[256];
    int t = threadIdx.x;
    int f = t & 127, rh = t >> 7;
    int r0 = blockIdx.x * 32 + rh * 16;
    float a = 0.f, b = 0.f;
#pragma unroll
    for (int rr = 0; rr < 16; ++rr) {
        float x = H[(size_t)(r0 + rr) * DIN + f];
        a += x; b += x * x;
    }
    s1[t] = a; s2[t] = b;
    __syncthreads();
    if (t < 128) {
        atomicAdd(&bns[f], s1[t] + s1[t + 128]);
        atomicAdd(&bns[128 + f], s2[t] + s2[t + 128]);
    }
    int gid = blockIdx.x * 256 + t;
    if (gid < 32768) {                       // Wt [128][256]
        int k = gid >> 8, c = gid & 255;
        WcatT[c * 128 + k] = (bf16)Wt[gid];
    } else if (gid < 40960) {                // W1 [128][64]
        int g = gid - 32768, k = g >> 6, c = g & 63;
        WcatT[(256 + c) * 128 + k] = (bf16)W1[g];
    } else if (gid < 49152) {                // W2 [128][64]
        int g = gid - 40960, k = g >> 6, c = g & 63;
        WcatT[(320 + c) * 128 + k] = (bf16)W2[g];
    }
}

// ---------------------------------------------------------------------------
// MFMA projection, block = 32 rows. Outputs: Hxs (swizzled bf16), out1 (fp32
// left half of out, coalesced via LDS), X2sw (swizzled bf16).
#define LDH2 136   // hn row stride (128+8)
#define LDX2 40    // x2s row stride (32+8)
#define LDO  68    // outs row stride f32 (64+4)

__global__ __launch_bounds__(256) void k_project(
    const float* __restrict__ H, const float* __restrict__ bns,
    const float* __restrict__ gamma, const float* __restrict__ beta,
    const bf16* __restrict__ WcatT, const float* __restrict__ bt,
    const float* __restrict__ b1, const float* __restrict__ b2,
    bf16* __restrict__ Hxs, bf16* __restrict__ X2sw, float* __restrict__ out)
{
    __shared__ __align__(16) bf16 hn[32 * LDH2];
    __shared__ __align__(16) bf16 hxs_stage[8192];   // 2 panels x 8 k x 512
    __shared__ __align__(16) bf16 x2s[64 * LDX2];
    __shared__ __align__(16) float outs[32 * LDO];
    int t = threadIdx.x;
    int w = t >> 6, l = t & 63, q = l >> 4, li = l & 15;
    int i0 = blockIdx.x * 32;
    {   // BN apply
        int c4 = (t & 31) * 4;
        float mean[4], sc[4], sh[4];
#pragma unroll
        for (int j = 0; j < 4; ++j) {
            int c = c4 + j;
            float m = bns[c] * (1.f / 8192.f);
            float v = bns[128 + c] * (1.f / 8192.f) - m * m;
            mean[j] = m; sc[j] = rsqrtf(v + 1e-5f) * gamma[c]; sh[j] = beta[c];
        }
#pragma unroll
        for (int p = 0; p < 4; ++p) {
            int row = (t >> 5) + 8 * p;
            float4 x = *(const float4*)&H[(size_t)(i0 + row) * DIN + c4];
            bf16x4 o;
            o[0] = (bf16)((x.x - mean[0]) * sc[0] + sh[0]);
            o[1] = (bf16)((x.y - mean[1]) * sc[1] + sh[1]);
            o[2] = (bf16)((x.z - mean[2]) * sc[2] + sh[2]);
            o[3] = (bf16)((x.w - mean[3]) * sc[3] + sh[3]);
            *(bf16x4*)&hn[row * LDH2 + c4] = o;
        }
    }
    __syncthreads();
    // [32 x 128] @ [128 x 384]; wave w owns n-cols [w*96, w*96+96)
    f32x4 acc[2][6] = {};
#pragma unroll
    for (int k = 0; k < 4; ++k) {
        bf16x8 af0 = *(const bf16x8*)&hn[li * LDH2 + k * 32 + q * 8];
        bf16x8 af1 = *(const bf16x8*)&hn[(16 + li) * LDH2 + k * 32 + q * 8];
#pragma unroll
        for (int j = 0; j < 6; ++j) {
            int c = w * 96 + j * 16 + li;
            bf16x8 bf_ = *(const bf16x8*)&WcatT[(size_t)c * 128 + k * 32 + q * 8];
            acc[0][j] = __builtin_amdgcn_mfma_f32_16x16x32_bf16(af0, bf_, acc[0][j], 0, 0, 0);
            acc[1][j] = __builtin_amdgcn_mfma_f32_16x16x32_bf16(af1, bf_, acc[1][j], 0, 0, 0);
        }
    }
    // epilogue into LDS staging buffers (branch uniform per (w,j))
#pragma unroll
    for (int j = 0; j < 6; ++j) {
        int c0 = w * 96 + j * 16 + li;
        if (c0 < 256) {
            float bb = bt[c0];
            int k = c0 >> 5, qd = (c0 >> 3) & 3, e = c0 & 7;
#pragma unroll
            for (int mt = 0; mt < 2; ++mt)
#pragma unroll
                for (int rr = 0; rr < 4; ++rr)
                    hxs_stage[((mt * 8 + k) * 64 + (q * 4 + rr) * 4 + qd) * 8 + e] =
                        (bf16)(acc[mt][j][rr] + bb);
        } else if (c0 < 320) {
            float bb = b1[c0 - 256];
#pragma unroll
            for (int mt = 0; mt < 2; ++mt)
#pragma unroll
                for (int rr = 0; rr < 4; ++rr) {
                    float v = acc[mt][j][rr] + bb;
                    outs[(mt * 16 + q * 4 + rr) * LDO + (c0 - 256)] =
                        v > 0.f ? v : 0.01f * v;
                }
        } else {
            float bb = b2[c0 - 320];
#pragma unroll
            for (int mt = 0; mt < 2; ++mt)
#pragma unroll
                for (int rr = 0; rr < 4; ++rr)
                    x2s[(c0 - 320) * LDX2 + mt * 16 + q * 4 + rr] =
                        (bf16)(acc[mt][j][rr] + bb);
        }
    }
    __syncthreads();
    // Hxs writeout: 8192 elems = 1024 b128 units, fully coalesced
#pragma unroll
    for (int p = 0; p < 4; ++p) {
        int u = t + p * 256;
        *(bf16x8*)&Hxs[(size_t)(i0 >> 4) * 4096 + u * 8] =
            *(const bf16x8*)&hxs_stage[u * 8];
    }
    // out1 writeout: 32 rows x 64 f32
#pragma unroll
    for (int p = 0; p < 2; ++p) {
        int u = t + p * 256;
        int row = u >> 4, c4 = (u & 15) * 4;
        *(float4*)&out[(size_t)(i0 + row) * 128 + c4] = *(const float4*)&outs[row * LDO + c4];
    }
    {   // X2sw writeout: block covers (jblk = i0>>6, ks = (i0>>5)&1)
        int jblk = i0 >> 6, ks = (i0 >> 5) & 1;
        int c = t >> 2, qq = t & 3;
        bf16x8 v = *(const bf16x8*)&x2s[c * LDX2 + qq * 8];
        *(bf16x8*)&X2sw[(size_t)(((((jblk * 4 + (c >> 4)) * 2 + ks) * 16 + (c & 15)) * 4 + qq)) * 8] = v;
    }
}

// ---------------------------------------------------------------------------
// Fused gate+aggregate. i-tile 32 (afrag persistent), j-split 4, 64-j chunks.
// All matrix fragments load straight from swizzled global (coalesced b128).
// A-mask: coalesced dword loads (2-chunk prefetch) -> __ballot -> dbuf LDS
// words. P C->A layout round-trip in dbuf LDS. ONE lgkm-only barrier/chunk.
//
// Race analysis (single barrier B(ch), all LDS double-buffered):
//  P[ch&1]:    write(gating ch, pre-B(ch)) -> B(ch) -> read(agg ch). Next
//              write at ch+2 is post-B(ch+1); reader's ds_reads drained by
//              lgkmcnt(0) at B(ch+1). safe.
//  maskw[b]:   written during ch (for ch+1, pre-B(ch)) -> read at gating
//              ch+1 (post-B(ch)). Next write during ch+2 (post-B(ch+1));
//              reads drained at B(ch+1). safe.
#define LDP 72    // P row stride (64+8)

__global__ __launch_bounds__(256, 3) void k_fused(
    const float* __restrict__ A, const bf16* __restrict__ Hxs,
    const bf16* __restrict__ X2sw, float* __restrict__ paccS,
    float* __restrict__ pdenS)
{
    __shared__ __align__(16) bf16 P[2][32 * LDP];
    __shared__ unsigned int maskw[2][32][2];

    int t = threadIdx.x;
    int w = t >> 6, l = t & 63, q = l >> 4, li = l & 15;
    int ib = blockIdx.x >> 2, js = blockIdx.x & 3;
    int i0 = ib * 32, jbase = js * 2048;

    // persistent A-side fragments: 32 i-rows, K=256, coalesced from Hxs
    bf16x8 afrag[2][8];
#pragma unroll
    for (int mt = 0; mt < 2; ++mt)
#pragma unroll
        for (int k = 0; k < 8; ++k)
            afrag[mt][k] = *(const bf16x8*)&Hxs[(size_t)((((i0 >> 4) + mt) * 8 + k) * 64 + li * 4 + q) * 8];

    // ballot source: lane covers A row i0 + w*8 + (p>>1)*2 + (l>>5),
    //                col (p&1)*32 + (l&31) + j0   (full 128B lines)
    const float* Arow = A + (size_t)(i0 + w * 8 + (l >> 5)) * NN + (l & 31);

    float av[2][8];
#pragma unroll
    for (int p = 0; p < 8; ++p)
        av[0][p] = Arow[((p >> 1) * 2) * NN + (p & 1) * 32 + jbase];
#pragma unroll
    for (int p = 0; p < 8; ++p)
        av[1][p] = Arow[((p >> 1) * 2) * NN + (p & 1) * 32 + jbase + 64];
    // mask for chunk 0
#pragma unroll
    for (int p = 0; p < 8; ++p) {
        unsigned long long bal = __ballot(av[0][p] > 0.f);
        int rr = w * 8 + (p >> 1) * 2;
        if (l == 0)       maskw[0][rr][p & 1]     = (unsigned int)bal;
        else if (l == 32) maskw[0][rr + 1][p & 1] = (unsigned int)(bal >> 32);
    }
    LGKM_BARRIER();

    f32x4 agg[2] = {};
    f32x4 agg4 = {};
    bf16 onev = (bf16)1.0f;
    bf16x8 ones = {onev, onev, onev, onev, onev, onev, onev, onev};
    int mw = w >> 1, cb0 = (w & 1) * 2;

    for (int ch = 0; ch < 32; ++ch) {
        int j0 = jbase + ch * 64;
        int jc = j0 + w * 16 + li;
        int buf = ch & 1;
        // issue A(ch+2) into slot[ch&1] (slot freed pre-loop / at ch-1)
        {
            int jA = jbase + (ch + 2 < 32 ? ch + 2 : 31) * 64;
#pragma unroll
            for (int p = 0; p < 8; ++p)
                av[buf][p] = Arow[((p >> 1) * 2) * NN + (p & 1) * 32 + jA];
        }
        // B-side fragments: wave's 16 j-rows from swizzled Hxs (coalesced)
        int pj = (j0 + w * 16) >> 4;
        bf16x8 bfr[8];
#pragma unroll
        for (int k = 0; k < 8; ++k)
            bfr[k] = *(const bf16x8*)&Hxs[(size_t)((pj * 8 + k) * 64 + li * 4 + q) * 8];
        // S = Hx_i @ Hx_j^T
        f32x4 s[2] = {};
#pragma unroll
        for (int k = 0; k < 8; ++k) {
            s[0] = __builtin_amdgcn_mfma_f32_16x16x32_bf16(afrag[0][k], bfr[k], s[0], 0, 0, 0);
            s[1] = __builtin_amdgcn_mfma_f32_16x16x32_bf16(afrag[1][k], bfr[k], s[1], 0, 0, 0);
        }
        // X2 fragments for agg (L2-hot, issued before gating for latency)
        int jblk = j0 >> 6;
        bf16x8 xf[2][2];
#pragma unroll
        for (int ks = 0; ks < 2; ++ks)
#pragma unroll
            for (int cbi = 0; cbi < 2; ++cbi)
                xf[ks][cbi] = *(const bf16x8*)&X2sw[(size_t)(((((jblk * 4 + cb0 + cbi) * 2 + ks) * 16 + li) * 4 + q)) * 8];
        // gating -> P[buf]
#pragma unroll
        for (int mt = 0; mt < 2; ++mt)
#pragma unroll
            for (int r = 0; r < 4; ++r) {
                int rloc = mt * 16 + q * 4 + r;
                unsigned int wd = maskw[buf][rloc][w >> 1];
                bool m = (wd >> ((w & 1) * 16 + li)) & 1u;
                float sv = s[mt][r];
                float sig = __builtin_amdgcn_rcpf(1.f + __expf(-sv));
                float wv = m ? __expf(sig) : 0.f;
                if (i0 + rloc == jc) wv = 2.71828182845904523f;
                P[buf][rloc * LDP + w * 16 + li] = (bf16)wv;
            }
        // mask for ch+1 (A data prefetched at ch-1; ~1.5 chunks in flight)
#pragma unroll
        for (int p = 0; p < 8; ++p) {
            unsigned long long bal = __ballot(av[buf ^ 1][p] > 0.f);
            int rr = w * 8 + (p >> 1) * 2;
            if (l == 0)       maskw[buf ^ 1][rr][p & 1]     = (unsigned int)bal;
            else if (l == 32) maskw[buf ^ 1][rr + 1][p & 1] = (unsigned int)(bal >> 32);
        }
        LGKM_BARRIER();
        // agg += P @ X2chunk (+ ones-column denominator)
#pragma unroll
        for (int ks = 0; ks < 2; ++ks) {
            bf16x8 pa = *(const bf16x8*)&P[buf][(mw * 16 + li) * LDP + ks * 32 + q * 8];
            agg[0] = __builtin_amdgcn_mfma_f32_16x16x32_bf16(pa, xf[ks][0], agg[0], 0, 0, 0);
            agg[1] = __builtin_amdgcn_mfma_f32_16x16x32_bf16(pa, xf[ks][1], agg[1], 0, 0, 0);
            agg4 = __builtin_amdgcn_mfma_f32_16x16x32_bf16(pa, ones, agg4, 0, 0, 0);
        }
    }

    // per-js slice writeout (each element written exactly once)
#pragma unroll
    for (int cbi = 0; cbi < 2; ++cbi)
#pragma unroll
        for (int r = 0; r < 4; ++r)
            paccS[(size_t)js * (8192 * 64) + (size_t)(i0 + mw * 16 + q * 4 + r) * DH + (cb0 + cbi) * 16 + li] =
                agg[cbi][r];
    if (((w & 1) == 0) && li == 0) {
#pragma unroll
        for (int r = 0; r < 4; ++r)
            pdenS[js * 8192 + i0 + mw * 16 + q * 4 + r] = agg4[r];
    }
}

// ---------------------------------------------------------------------------
__global__ __launch_bounds__(256) void k_finalize(const float* __restrict__ paccS,
                                                  const float* __restrict__ pdenS,
                                                  float* __restrict__ out)
{
    int e = blockIdx.x * 256 + threadIdx.x;
    int i = e >> 6, c = e & 63;
    float num = 0.f, den = 0.f;
#pragma unroll
    for (int js = 0; js < 4; ++js) {
        num += paccS[(size_t)js * (8192 * 64) + e];
        den += pdenS[js * 8192 + i];
    }
    float v = num / den;
    out[(size_t)i * 128 + 64 + c] = v > 0.f ? v : 0.01f * v;
}

// ---------------------------------------------------------------------------
extern "C" void kernel_launch(void* const* d_in, const int* in_sizes, int n_in,
                              void* d_out, int out_size, void* d_ws, size_t ws_size,
                              hipStream_t stream)
{
    const float* H     = (const float*)d_in[0];
    const float* A     = (const float*)d_in[1];
    const float* gamma = (const float*)d_in[2];
    const float* beta  = (const float*)d_in[3];
    const float* Wt    = (const float*)d_in[4];
    const float* bt    = (const float*)d_in[5];
    const float* W1    = (const float*)d_in[6];
    const float* b1    = (const float*)d_in[7];
    const float* W2    = (const float*)d_in[8];
    const float* b2    = (const float*)d_in[9];
    float* out = (float*)d_out;

    char* ws = (char*)d_ws;
    float* paccS = (float*)(ws + OFF_PACCS);
    float* pdenS = (float*)(ws + OFF_PDENS);
    float* bns   = (float*)(ws + OFF_BN);
    bf16*  Hxs   = (bf16*)(ws + OFF_HXS);
    bf16*  X2sw  = (bf16*)(ws + OFF_X2SW);
    bf16*  WcatT = (bf16*)(ws + OFF_WCT);

    hipMemsetAsync(bns, 0, 1024, stream);
    k_bn_stats<<<256, 256, 0, stream>>>(H, bns, Wt, W1, W2, WcatT);
    k_project<<<256, 256, 0, stream>>>(H, bns, gamma, beta, WcatT, bt, b1, b2,
                                       Hxs, X2sw, out);
    k_fused<<<1024, 256, 0, stream>>>(A, Hxs, X2sw, paccS, pdenS);
    k_finalize<<<2048, 256, 0, stream>>>(paccS, pdenS, out);
}

// Round 5
// 519.603 us; speedup vs baseline: 1.1995x; 1.1995x over previous
//
#include <hip/hip_runtime.h>
#include <hip/hip_bf16.h>

typedef __bf16 bf16;
typedef __bf16 bf16x8 __attribute__((ext_vector_type(8)));
typedef __bf16 bf16x4 __attribute__((ext_vector_type(4)));
typedef float f32x4 __attribute__((ext_vector_type(4)));

// problem sizes
#define NN 8192
#define DIN 128
#define DTH 256
#define DH 64

// workspace layout (bytes)
#define OFF_PACCS 0                          // [8 js][8192][64] f32 partial agg (16 MB)
#define OFF_PDENS (8*8192*64*4)              // [8 js][8192] f32 partial denom (256 KB)
#define OFF_BN    (OFF_PDENS + 8*8192*4)     // 256 f32 bn sums (needs zero)
#define OFF_HXS   (OFF_BN + 1024)            // swizzled Hx: 8192*256 bf16 (4 MB)
#define OFF_X2SW  (OFF_HXS + 8192*256*2)     // X2 j-blocked: [256 jb][64 c][32 j] (1 MB)
#define OFF_MASK  (OFF_X2SW + 64*8192*2)     // maskT: [256 jw][8192 i] u32 (8 MB)
#define OFF_WCT   (OFF_MASK + 256*8192*4)    // [384][128] bf16 W concat^T

// Hxs swizzle: element (row, kk) -> ((row>>4)*8 + (kk>>5))*512
//                                   + ((row&15)*4 + ((kk>>3)&3))*8 + (kk&7)
// MFMA frag (panel p, k): lane(q,li) loads b128 at ((p*8+k)*64 + li*4+q)*8.

// ---------------------------------------------------------------------------
// BN statistics (atomic per-feature sum/sumsq) + cast W -> WcatT bf16.
__global__ __launch_bounds__(256) void k_bn_stats(
    const float* __restrict__ H, float* __restrict__ bns,
    const float* __restrict__ Wt, const float* __restrict__ W1,
    const float* __restrict__ W2, bf16* __restrict__ WcatT)
{
    __shared__ float s1[256], s2[256];
    int t = threadIdx.x;
    int f = t & 127, rh = t >> 7;
    int r0 = blockIdx.x * 32 + rh * 16;
    float a = 0.f, b = 0.f;
#pragma unroll
    for (int rr = 0; rr < 16; ++rr) {
        float x = H[(size_t)(r0 + rr) * DIN + f];
        a += x; b += x * x;
    }
    s1[t] = a; s2[t] = b;
    __syncthreads();
    if (t < 128) {
        atomicAdd(&bns[f], s1[t] + s1[t + 128]);
        atomicAdd(&bns[128 + f], s2[t] + s2[t + 128]);
    }
    int gid = blockIdx.x * 256 + t;
    if (gid < 32768) {                       // Wt [128][256]
        int k = gid >> 8, c = gid & 255;
        WcatT[c * 128 + k] = (bf16)Wt[gid];
    } else if (gid < 40960) {                // W1 [128][64]
        int g = gid - 32768, k = g >> 6, c = g & 63;
        WcatT[(256 + c) * 128 + k] = (bf16)W1[g];
    } else if (gid < 49152) {                // W2 [128][64]
        int g = gid - 40960, k = g >> 6, c = g & 63;
        WcatT[(320 + c) * 128 + k] = (bf16)W2[g];
    }
}

// ---------------------------------------------------------------------------
// A (fp32 0/1, 256 MB) -> transposed bitmask maskT[jw][i] (8 MB). Pure HBM.
__global__ __launch_bounds__(256) void k_mask(const float* __restrict__ A,
                                              unsigned int* __restrict__ maskT)
{
    int t = threadIdx.x, w = t >> 6, l = t & 63;
    int i0 = (blockIdx.x >> 4) * 64 + w * 16;
    int jw0 = (blockIdx.x & 15) * 16;
#pragma unroll
    for (int rr = 0; rr < 8; ++rr) {
        int row = i0 + rr * 2 + (l >> 5);
        const float* ap = &A[(size_t)row * NN + (l & 31)];
#pragma unroll
        for (int jw = 0; jw < 16; ++jw) {
            int jwg = jw0 + jw;
            float v = ap[(size_t)jwg * 32];
            unsigned long long bal = __ballot(v > 0.f);
            if (l == 0)       maskT[(size_t)jwg * NN + row] = (unsigned int)bal;
            else if (l == 32) maskT[(size_t)jwg * NN + row] = (unsigned int)(bal >> 32);
        }
    }
}

// ---------------------------------------------------------------------------
// MFMA projection, block = 32 rows. Outputs: Hxs (swizzled), out1 (fp32 left
// half), X2sw [jb=i0/32][c][j&31] (block covers exactly one jb).
#define LDH2 136   // hn row stride (128+8)
#define LDX2 40    // x2s row stride (32+8)
#define LDO  68    // outs row stride f32 (64+4)

__global__ __launch_bounds__(256) void k_project(
    const float* __restrict__ H, const float* __restrict__ bns,
    const float* __restrict__ gamma, const float* __restrict__ beta,
    const bf16* __restrict__ WcatT, const float* __restrict__ bt,
    const float* __restrict__ b1, const float* __restrict__ b2,
    bf16* __restrict__ Hxs, bf16* __restrict__ X2sw, float* __restrict__ out)
{
    __shared__ __align__(16) bf16 hn[32 * LDH2];
    __shared__ __align__(16) bf16 hxs_stage[8192];   // 2 panels x 8 k x 512
    __shared__ __align__(16) bf16 x2s[64 * LDX2];
    __shared__ __align__(16) float outs[32 * LDO];
    int t = threadIdx.x;
    int w = t >> 6, l = t & 63, q = l >> 4, li = l & 15;
    int i0 = blockIdx.x * 32;
    {   // BN apply
        int c4 = (t & 31) * 4;
        float mean[4], sc[4], sh[4];
#pragma unroll
        for (int j = 0; j < 4; ++j) {
            int c = c4 + j;
            float m = bns[c] * (1.f / 8192.f);
            float v = bns[128 + c] * (1.f / 8192.f) - m * m;
            mean[j] = m; sc[j] = rsqrtf(v + 1e-5f) * gamma[c]; sh[j] = beta[c];
        }
#pragma unroll
        for (int p = 0; p < 4; ++p) {
            int row = (t >> 5) + 8 * p;
            float4 x = *(const float4*)&H[(size_t)(i0 + row) * DIN + c4];
            bf16x4 o;
            o[0] = (bf16)((x.x - mean[0]) * sc[0] + sh[0]);
            o[1] = (bf16)((x.y - mean[1]) * sc[1] + sh[1]);
            o[2] = (bf16)((x.z - mean[2]) * sc[2] + sh[2]);
            o[3] = (bf16)((x.w - mean[3]) * sc[3] + sh[3]);
            *(bf16x4*)&hn[row * LDH2 + c4] = o;
        }
    }
    __syncthreads();
    // [32 x 128] @ [128 x 384]; wave w owns n-cols [w*96, w*96+96)
    f32x4 acc[2][6] = {};
#pragma unroll
    for (int k = 0; k < 4; ++k) {
        bf16x8 af0 = *(const bf16x8*)&hn[li * LDH2 + k * 32 + q * 8];
        bf16x8 af1 = *(const bf16x8*)&hn[(16 + li) * LDH2 + k * 32 + q * 8];
#pragma unroll
        for (int j = 0; j < 6; ++j) {
            int c = w * 96 + j * 16 + li;
            bf16x8 bf_ = *(const bf16x8*)&WcatT[(size_t)c * 128 + k * 32 + q * 8];
            acc[0][j] = __builtin_amdgcn_mfma_f32_16x16x32_bf16(af0, bf_, acc[0][j], 0, 0, 0);
            acc[1][j] = __builtin_amdgcn_mfma_f32_16x16x32_bf16(af1, bf_, acc[1][j], 0, 0, 0);
        }
    }
    // epilogue into LDS staging buffers (branch uniform per (w,j))
#pragma unroll
    for (int j = 0; j < 6; ++j) {
        int c0 = w * 96 + j * 16 + li;
        if (c0 < 256) {
            float bb = bt[c0];
            int k = c0 >> 5, qd = (c0 >> 3) & 3, e = c0 & 7;
#pragma unroll
            for (int mt = 0; mt < 2; ++mt)
#pragma unroll
                for (int rr = 0; rr < 4; ++rr)
                    hxs_stage[((mt * 8 + k) * 64 + (q * 4 + rr) * 4 + qd) * 8 + e] =
                        (bf16)(acc[mt][j][rr] + bb);
        } else if (c0 < 320) {
            float bb = b1[c0 - 256];
#pragma unroll
            for (int mt = 0; mt < 2; ++mt)
#pragma unroll
                for (int rr = 0; rr < 4; ++rr) {
                    float v = acc[mt][j][rr] + bb;
                    outs[(mt * 16 + q * 4 + rr) * LDO + (c0 - 256)] =
                        v > 0.f ? v : 0.01f * v;
                }
        } else {
            float bb = b2[c0 - 320];
#pragma unroll
            for (int mt = 0; mt < 2; ++mt)
#pragma unroll
                for (int rr = 0; rr < 4; ++rr)
                    x2s[(c0 - 320) * LDX2 + mt * 16 + q * 4 + rr] =
                        (bf16)(acc[mt][j][rr] + bb);
        }
    }
    __syncthreads();
    // Hxs writeout: fully coalesced
#pragma unroll
    for (int p = 0; p < 4; ++p) {
        int u = t + p * 256;
        *(bf16x8*)&Hxs[(size_t)(i0 >> 4) * 4096 + u * 8] =
            *(const bf16x8*)&hxs_stage[u * 8];
    }
    // out1 writeout
#pragma unroll
    for (int p = 0; p < 2; ++p) {
        int u = t + p * 256;
        int row = u >> 4, c4 = (u & 15) * 4;
        *(float4*)&out[(size_t)(i0 + row) * 128 + c4] = *(const float4*)&outs[row * LDO + c4];
    }
    {   // X2sw writeout: this block is j-rows [i0, i0+32) = jb = i0>>5
        int jb = i0 >> 5;
        int c = t >> 2, sg = t & 3;
        *(bf16x8*)&X2sw[(size_t)jb * 2048 + c * 32 + sg * 8] =
            *(const bf16x8*)&x2s[c * LDX2 + sg * 8];
    }
}

// ---------------------------------------------------------------------------
// Barrier-free fused gate+aggregate.
// Wave owns 32 i-rows; computes S^T = Hx_j @ Hx_i^T so the MFMA C-layout
// lands (i=li, j=q*4+r) -- the layout transform to the agg MFMA's A-operand
// (m=li, k=q*8+e) is wave-private: 4 ds_write_b64 + 2 ds_read_b128 into a
// private LDS strip, ordered by in-wave lgkmcnt only. NO __syncthreads.
// Mask from pre-packed maskT (1 u32 covers a whole 32-j chunk per i-row).
// Grid 512 = 64 i-blocks x 8 js; js == XCD (blockIdx%8) for L2 locality.
#define LDPS 48   // P-stage row stride in elements (96 B, b128-aligned)

__global__ __launch_bounds__(256) void k_fused(
    const unsigned int* __restrict__ maskT, const bf16* __restrict__ Hxs,
    const bf16* __restrict__ X2sw, float* __restrict__ paccS,
    float* __restrict__ pdenS)
{
    __shared__ __align__(16) bf16 Pst[128 * LDPS];   // 4 waves x 32 rows
    int t = threadIdx.x;
    int w = t >> 6, l = t & 63, q = l >> 4, li = l & 15;
    int ibb = blockIdx.x >> 3, js = blockIdx.x & 7;
    int i0w = ibb * 128 + w * 32;
    int jsb = js * 1024;
    bf16* myP = &Pst[(w * 32) * LDPS];

    // persistent i-side fragments (B-operand of S^T): 32 i-rows, K=256
    bf16x8 ifrag[2][8];
#pragma unroll
    for (int it = 0; it < 2; ++it)
#pragma unroll
        for (int k = 0; k < 8; ++k)
            ifrag[it][k] = *(const bf16x8*)&Hxs[(size_t)((((i0w >> 4) + it) * 8 + k) * 64 + li * 4 + q) * 8];

    f32x4 acc[2][4] = {};
    float dsum[2] = {0.f, 0.f};

    for (int ch = 0; ch < 32; ++ch) {
        int j0 = jsb + ch * 32;
        int jb = j0 >> 5;
        // mask words: 1 u32 per i-row covers this whole 32-j chunk
        unsigned int mwv[2];
        mwv[0] = maskT[(size_t)jb * NN + i0w + li];
        mwv[1] = maskT[(size_t)jb * NN + i0w + 16 + li];
        // X2 B-fragments (K=32): lane (q,li) -> c = ct*16+li, j = q*8+e
        bf16x8 xf[4];
#pragma unroll
        for (int ct = 0; ct < 4; ++ct)
            xf[ct] = *(const bf16x8*)&X2sw[(size_t)jb * 2048 + (ct * 16 + li) * 32 + q * 8];

        bf16x4 pk[2][2];
#pragma unroll
        for (int jt = 0; jt < 2; ++jt) {
            int pj = (j0 + jt * 16) >> 4;
            bf16x8 jf[8];
#pragma unroll
            for (int k = 0; k < 8; ++k)
                jf[k] = *(const bf16x8*)&Hxs[(size_t)((pj * 8 + k) * 64 + li * 4 + q) * 8];
            f32x4 st0 = {}, st1 = {};
#pragma unroll
            for (int k = 0; k < 8; ++k) {
                st0 = __builtin_amdgcn_mfma_f32_16x16x32_bf16(jf[k], ifrag[0][k], st0, 0, 0, 0);
                st1 = __builtin_amdgcn_mfma_f32_16x16x32_bf16(jf[k], ifrag[1][k], st1, 0, 0, 0);
            }
            // gate: (i = i0w+it*16+li, j = j0+jt*16+q*4+r)
#pragma unroll
            for (int it = 0; it < 2; ++it) {
                f32x4 sv = it ? st1 : st0;
                bf16x4 pkk;
#pragma unroll
                for (int r = 0; r < 3 + 1; ++r) {
                    int jj = j0 + jt * 16 + q * 4 + r;
                    float s = sv[r];
                    float sig = __builtin_amdgcn_rcpf(1.f + __expf(-s));
                    bool m = (mwv[it] >> (jt * 16 + q * 4 + r)) & 1u;
                    float wv = m ? __expf(sig) : 0.f;
                    if (i0w + it * 16 + li == jj) wv = 2.71828182845904523f;
                    dsum[it] += wv;
                    pkk[r] = (bf16)wv;
                }
                pk[it][jt] = pkk;
            }
        }
        // wave-private C->A layout transform (in-wave lgkm ordering only)
#pragma unroll
        for (int it = 0; it < 2; ++it)
#pragma unroll
            for (int jt = 0; jt < 2; ++jt)
                *(bf16x4*)&myP[(it * 16 + li) * LDPS + jt * 16 + q * 4] = pk[it][jt];
        bf16x8 pf[2];
#pragma unroll
        for (int it = 0; it < 2; ++it)
            pf[it] = *(const bf16x8*)&myP[(it * 16 + li) * LDPS + q * 8];
        // agg += P @ X2chunk
#pragma unroll
        for (int it = 0; it < 2; ++it)
#pragma unroll
            for (int ct = 0; ct < 4; ++ct)
                acc[it][ct] = __builtin_amdgcn_mfma_f32_16x16x32_bf16(pf[it], xf[ct], acc[it][ct], 0, 0, 0);
    }

    // per-js slice writeout (each element written exactly once)
#pragma unroll
    for (int it = 0; it < 2; ++it)
#pragma unroll
        for (int ct = 0; ct < 4; ++ct)
#pragma unroll
            for (int r = 0; r < 4; ++r)
                paccS[(size_t)js * (8192 * 64) + (size_t)(i0w + it * 16 + q * 4 + r) * DH + ct * 16 + li] =
                    acc[it][ct][r];
    // denominator: reduce across the 4 q-groups (lanes ^16, ^32)
#pragma unroll
    for (int it = 0; it < 2; ++it) {
        float v = dsum[it];
        v += __shfl_xor(v, 16, 64);
        v += __shfl_xor(v, 32, 64);
        if (l < 16) pdenS[js * 8192 + i0w + it * 16 + l] = v;
    }
}

// ---------------------------------------------------------------------------
__global__ __launch_bounds__(256) void k_finalize(const float* __restrict__ paccS,
                                                  const float* __restrict__ pdenS,
                                                  float* __restrict__ out)
{
    int e = blockIdx.x * 256 + threadIdx.x;
    int i = e >> 6, c = e & 63;
    float num = 0.f, den = 0.f;
#pragma unroll
    for (int js = 0; js < 8; ++js) {
        num += paccS[(size_t)js * (8192 * 64) + e];
        den += pdenS[js * 8192 + i];
    }
    float v = num / den;
    out[(size_t)i * 128 + 64 + c] = v > 0.f ? v : 0.01f * v;
}

// ---------------------------------------------------------------------------
extern "C" void kernel_launch(void* const* d_in, const int* in_sizes, int n_in,
                              void* d_out, int out_size, void* d_ws, size_t ws_size,
                              hipStream_t stream)
{
    const float* H     = (const float*)d_in[0];
    const float* A     = (const float*)d_in[1];
    const float* gamma = (const float*)d_in[2];
    const float* beta  = (const float*)d_in[3];
    const float* Wt    = (const float*)d_in[4];
    const float* bt    = (const float*)d_in[5];
    const float* W1    = (const float*)d_in[6];
    const float* b1    = (const float*)d_in[7];
    const float* W2    = (const float*)d_in[8];
    const float* b2    = (const float*)d_in[9];
    float* out = (float*)d_out;

    char* ws = (char*)d_ws;
    float* paccS = (float*)(ws + OFF_PACCS);
    float* pdenS = (float*)(ws + OFF_PDENS);
    float* bns   = (float*)(ws + OFF_BN);
    bf16*  Hxs   = (bf16*)(ws + OFF_HXS);
    bf16*  X2sw  = (bf16*)(ws + OFF_X2SW);
    unsigned int* maskT = (unsigned int*)(ws + OFF_MASK);
    bf16*  WcatT = (bf16*)(ws + OFF_WCT);

    hipMemsetAsync(bns, 0, 1024, stream);
    k_bn_stats<<<256, 256, 0, stream>>>(H, bns, Wt, W1, W2, WcatT);
    k_mask<<<2048, 256, 0, stream>>>(A, maskT);
    k_project<<<256, 256, 0, stream>>>(H, bns, gamma, beta, WcatT, bt, b1, b2,
                                       Hxs, X2sw, out);
    k_fused<<<512, 256, 0, stream>>>(maskT, Hxs, X2sw, paccS, pdenS);
    k_finalize<<<2048, 256, 0, stream>>>(paccS, pdenS, out);
}